// Round 4
// baseline (139.219 us; speedup 1.0000x reference)
//
#include <hip/hip_runtime.h>
#include <hip/hip_bf16.h>

#define N_CURR 4096
#define M_PREV 10240
#define DIM 256
#define BM 128
#define BN 128
#define BK 32
#define NBX (M_PREV / BN)   // 80
#define NBY (N_CURR / BM)   // 32
#define NBLK (NBX * NBY)    // 2560

typedef short short8 __attribute__((ext_vector_type(8)));
typedef float f32x4 __attribute__((ext_vector_type(4)));

__device__ __forceinline__ unsigned short f2bf(float f) {
  union { float f; unsigned int u; } x; x.f = f;
  unsigned int u = x.u;
  return (unsigned short)((u + 0x7fffu + ((u >> 16) & 1u)) >> 16);  // RNE
}

// One wave per row: squared norm, inv-norm, bf16 cast, centers.
// Packs {invn, |x|^2, cx, cy} into one float4 per row.
__global__ __launch_bounds__(256) void prep_kernel(
    const float* __restrict__ ce, const float* __restrict__ cbx,
    const float* __restrict__ pe, const float* __restrict__ pbx,
    ushort* __restrict__ cbf, ushort* __restrict__ pbf,
    float4* __restrict__ cpar, float4* __restrict__ ppar)
{
  int gw = (blockIdx.x * 256 + threadIdx.x) >> 6;   // global wave = row
  int lane = threadIdx.x & 63;
  bool isCurr = gw < N_CURR;
  int row = isCurr ? gw : gw - N_CURR;
  const float* src = (isCurr ? ce : pe) + (size_t)row * DIM;
  ushort* dst = (isCurr ? cbf : pbf) + (size_t)row * DIM;

  float4 v = ((const float4*)src)[lane];            // 64 lanes x 16B = full row
  ushort4 b;
  b.x = f2bf(v.x); b.y = f2bf(v.y); b.z = f2bf(v.z); b.w = f2bf(v.w);
  ((ushort4*)dst)[lane] = b;

  float s = v.x*v.x + v.y*v.y + v.z*v.z + v.w*v.w;
  #pragma unroll
  for (int m = 32; m; m >>= 1) s += __shfl_xor(s, m);

  if (lane == 0) {
    float nrm = fmaxf(__builtin_amdgcn_sqrtf(s), 1e-12f);
    float4 bb = ((const float4*)(isCurr ? cbx : pbx))[row];
    float4 par;
    par.x = 1.0f / nrm;           // inv norm
    par.y = s;                    // squared norm
    par.z = bb.x + 0.5f * bb.z;   // center x
    par.w = bb.y + 0.5f * bb.w;   // center y
    (isCurr ? cpar : ppar)[row] = par;
  }
}

// 128x128 tile GEMM with NO LDS staging: operands are 7 MB total (L2/L3
// resident after prep), so each wave loads MFMA fragments directly from
// global. Zero barriers in the K loop -> compiler software-pipelines the
// loads with counted vmcnt. MFMA operands swapped (A=prev, B=curr) so each
// lane's 4 acc regs are 4 consecutive prev-columns -> float4 stores.
__global__ __launch_bounds__(256) void main_kernel(
    const ushort* __restrict__ cbf, const ushort* __restrict__ pbf,
    const float4* __restrict__ cpar, const float4* __restrict__ ppar,
    const int* __restrict__ cid, const int* __restrict__ pid,
    float* __restrict__ out, float* __restrict__ partials)
{
  __shared__ float4 rowv[BM];                      // {invnc, c2, cx, cy}
  __shared__ float4 colv[BN];                      // {invnp, p2, px, py}
  __shared__ int ridl[BM];
  __shared__ int cidl[BN];
  __shared__ float wsum[4];

  const int bid = blockIdx.x;
  const int bx = bid % NBX;
  const int by = bid / NBX;
  const int r0 = by * BM;
  const int c0 = bx * BN;
  const int tid = threadIdx.x;
  const int lane = tid & 63;
  const int wid = tid >> 6;

  if (tid < BM) {
    rowv[tid] = cpar[r0 + tid];
    ridl[tid] = cid[r0 + tid];
  } else {
    int t = tid - BM;
    colv[t] = ppar[c0 + t];
    cidl[t] = pid[c0 + t];
  }
  __syncthreads();

  const int wr = wid >> 1, wc = wid & 1;   // 2x2 wave grid, 64x64 per wave
  const int rb = wr * 64, cbase = wc * 64;
  const int frow = lane & 15;
  const int fko = (lane >> 4) * 8;         // k element offset (16B steps)

  // Fragment bases: per instruction a wave reads 16 rows x 64B contiguous.
  const ushort* aBase = cbf + (size_t)(r0 + rb + frow) * DIM + fko;
  const ushort* bBase = pbf + (size_t)(c0 + cbase + frow) * DIM + fko;

  f32x4 acc[4][4];   // [n][m]
  #pragma unroll
  for (int n = 0; n < 4; ++n)
    #pragma unroll
    for (int m = 0; m < 4; ++m)
      acc[n][m] = (f32x4){0.f, 0.f, 0.f, 0.f};

  #pragma unroll 2
  for (int ks = 0; ks < DIM / BK; ++ks) {
    const int k0 = ks * BK;
    short8 af[4], bfr[4];
    #pragma unroll
    for (int m = 0; m < 4; ++m)
      af[m] = *(const short8*)(aBase + (size_t)(m * 16) * DIM + k0);
    #pragma unroll
    for (int n = 0; n < 4; ++n)
      bfr[n] = *(const short8*)(bBase + (size_t)(n * 16) * DIM + k0);
    #pragma unroll
    for (int n = 0; n < 4; ++n)
      #pragma unroll
      for (int m = 0; m < 4; ++m)
        acc[n][m] = __builtin_amdgcn_mfma_f32_16x16x32_bf16(bfr[n], af[m], acc[n][m], 0, 0, 0);
  }

  // Epilogue: lane owns row i = rb + m*16 + (lane&15),
  //           cols j = cbase + n*16 + (lane>>4)*4 + r  (4 consecutive).
  float lp = 0.f;
  const int fi = lane & 15;
  const int g4 = (lane >> 4) << 2;
  #pragma unroll
  for (int m = 0; m < 4; ++m) {
    int il = rb + m*16 + fi;
    float4 rv = rowv[il];
    int rid = ridl[il];
    float* orow = out + (size_t)(r0 + il) * M_PREV + c0;
    #pragma unroll
    for (int n = 0; n < 4; ++n) {
      int jl0 = cbase + n*16 + g4;
      f32x4 res;
      #pragma unroll
      for (int r = 0; r < 4; ++r) {
        int jl = jl0 + r;
        float4 cv = colv[jl];
        float dot = acc[n][m][r];
        float cs = 1.0f - dot * rv.x * cv.x;
        float dx = rv.z - cv.z;
        float dy = rv.w - cv.w;
        float ccd = __builtin_amdgcn_sqrtf(dx*dx + dy*dy);
        res[r] = 0.7f * cs + 0.3f * ccd;
        float d2 = fmaxf(rv.y + cv.y - 2.0f * dot, 0.0f);
        float dist = __builtin_amdgcn_sqrtf(d2);
        float tt = fmaxf(1.0f - dist, 0.0f);
        lp += (rid == cidl[jl]) ? d2 : tt * tt;
      }
      __builtin_nontemporal_store(res, (f32x4*)(orow + jl0));
    }
  }

  #pragma unroll
  for (int m = 32; m; m >>= 1) lp += __shfl_xor(lp, m);
  if (lane == 0) wsum[wid] = lp;
  __syncthreads();
  if (tid == 0) partials[bid] = (wsum[0] + wsum[1]) + (wsum[2] + wsum[3]);
}

// Deterministic fixed-order reduction of block partials.
__global__ __launch_bounds__(256) void finalize_loss(
    const float* __restrict__ partials, float* __restrict__ loss_out)
{
  __shared__ float sh[4];
  float s = 0.f;
  for (int i = threadIdx.x; i < NBLK; i += 256) s += partials[i];
  #pragma unroll
  for (int m = 32; m; m >>= 1) s += __shfl_xor(s, m);
  if ((threadIdx.x & 63) == 0) sh[threadIdx.x >> 6] = s;
  __syncthreads();
  if (threadIdx.x == 0)
    loss_out[0] = ((sh[0] + sh[1]) + (sh[2] + sh[3])) * (1.0f / 41943040.0f);
}

extern "C" void kernel_launch(void* const* d_in, const int* in_sizes, int n_in,
                              void* d_out, int out_size, void* d_ws, size_t ws_size,
                              hipStream_t stream) {
  const float* ce  = (const float*)d_in[0];
  const float* cbx = (const float*)d_in[1];
  const float* pe  = (const float*)d_in[2];
  const float* pbx = (const float*)d_in[3];
  const int*   cid = (const int*)d_in[4];
  const int*   pid = (const int*)d_in[5];
  float* out = (float*)d_out;

  char* ws = (char*)d_ws;
  ushort* cbf = (ushort*)ws;                        // 4096*256*2  = 2 MB
  ushort* pbf = (ushort*)(ws + (2u << 20));         // 10240*256*2 = 5 MB
  float4* cpar = (float4*)(ws + 7340032);           // 64 KB
  float4* ppar = (float4*)(ws + 7340032 + 65536);   // 160 KB
  float* partials = (float*)(ws + 7340032 + 65536 + 163840);  // 10 KB

  prep_kernel<<<(N_CURR + M_PREV) / 4, 256, 0, stream>>>(
      ce, cbx, pe, pbx, cbf, pbf, cpar, ppar);
  main_kernel<<<NBLK, 256, 0, stream>>>(
      cbf, pbf, cpar, ppar, cid, pid, out, partials);
  finalize_loss<<<1, 256, 0, stream>>>(partials, out + (size_t)N_CURR * M_PREV);
}

// Round 5
// 112.627 us; speedup vs baseline: 1.2361x; 1.2361x over previous
//
#include <hip/hip_runtime.h>
#include <hip/hip_bf16.h>

#define N_CURR 4096
#define M_PREV 10240
#define DIM 256
#define BM 128
#define BN 128
#define BK 32
#define NBX (M_PREV / BN)   // 80
#define NBY (N_CURR / BM)   // 32
#define NBLK (NBX * NBY)    // 2560

typedef short short8 __attribute__((ext_vector_type(8)));
typedef float f32x4 __attribute__((ext_vector_type(4)));

__device__ __forceinline__ unsigned short f2bf(float f) {
  union { float f; unsigned int u; } x; x.f = f;
  unsigned int u = x.u;
  return (unsigned short)((u + 0x7fffu + ((u >> 16) & 1u)) >> 16);  // RNE
}

__device__ __forceinline__ void async16(const void* g, void* l) {
  __builtin_amdgcn_global_load_lds(
      (const __attribute__((address_space(1))) unsigned int*)g,
      (__attribute__((address_space(3))) unsigned int*)l, 16, 0, 0);
}

// One wave per row: squared norm, inv-norm, bf16 cast, centers.
// Packs {invn, |x|^2, cx, cy} into one float4 per row.
__global__ __launch_bounds__(256) void prep_kernel(
    const float* __restrict__ ce, const float* __restrict__ cbx,
    const float* __restrict__ pe, const float* __restrict__ pbx,
    ushort* __restrict__ cbf, ushort* __restrict__ pbf,
    float4* __restrict__ cpar, float4* __restrict__ ppar)
{
  int gw = (blockIdx.x * 256 + threadIdx.x) >> 6;   // global wave = row
  int lane = threadIdx.x & 63;
  bool isCurr = gw < N_CURR;
  int row = isCurr ? gw : gw - N_CURR;
  const float* src = (isCurr ? ce : pe) + (size_t)row * DIM;
  ushort* dst = (isCurr ? cbf : pbf) + (size_t)row * DIM;

  float4 v = ((const float4*)src)[lane];            // 64 lanes x 16B = full row
  ushort4 b;
  b.x = f2bf(v.x); b.y = f2bf(v.y); b.z = f2bf(v.z); b.w = f2bf(v.w);
  ((ushort4*)dst)[lane] = b;

  float s = v.x*v.x + v.y*v.y + v.z*v.z + v.w*v.w;
  #pragma unroll
  for (int m = 32; m; m >>= 1) s += __shfl_xor(s, m);

  if (lane == 0) {
    float nrm = fmaxf(__builtin_amdgcn_sqrtf(s), 1e-12f);
    float4 bb = ((const float4*)(isCurr ? cbx : pbx))[row];
    float4 par;
    par.x = 1.0f / nrm;           // inv norm
    par.y = s;                    // squared norm
    par.z = bb.x + 0.5f * bb.z;   // center x
    par.w = bb.y + 0.5f * bb.w;   // center y
    (isCurr ? cpar : ppar)[row] = par;
  }
}

// 128x128 tile NT-GEMM (dot = curr . prev) + fused epilogue.
// LDS-staged (operands L2-resident but LDS pipeline hides latency), MFMA
// operands swapped (A=prev, B=curr) so each lane's 4 acc regs are 4
// consecutive prev-columns -> float4 stores.
__global__ __launch_bounds__(256, 4) void main_kernel(
    const ushort* __restrict__ cbf, const ushort* __restrict__ pbf,
    const float4* __restrict__ cpar, const float4* __restrict__ ppar,
    const int* __restrict__ cid, const int* __restrict__ pid,
    float* __restrict__ out, float* __restrict__ partials)
{
  __shared__ __align__(16) ushort Al[2][BM][BK];   // 16 KB
  __shared__ __align__(16) ushort Bl[2][BN][BK];   // 16 KB
  __shared__ float4 rowv[BM];                      // {invnc, c2, cx, cy}
  __shared__ float4 colv[BN];                      // {0.7*invnp, p2, px, py}
  __shared__ int ridl[BM];
  __shared__ int cidl[BN];
  __shared__ float wsum[4];

  const int bid = blockIdx.x;
  const int bx = bid % NBX;
  const int by = bid / NBX;
  const int r0 = by * BM;
  const int c0 = bx * BN;
  const int tid = threadIdx.x;
  const int lane = tid & 63;
  const int wid = tid >> 6;

  // Stage per-row / per-col params into LDS (covered by first loop barrier).
  if (tid < BM) {
    rowv[tid] = cpar[r0 + tid];
    ridl[tid] = cid[r0 + tid];
  } else {
    int t = tid - BM;
    float4 pv = ppar[c0 + t];
    pv.x *= 0.7f;                                  // pre-scale by ALPHA
    colv[t] = pv;
    cidl[t] = pid[c0 + t];
  }

  const int lrow = lane >> 2;                       // 0..15 row within chunk
  // Source-side XOR swizzle (chunk ^= (row>>1)&3) so LDS reads are 2-way max.
  const int lk = (((lane & 3) ^ ((lrow >> 1) & 3)) * 8);

  // Each wave stages 32 rows of A and of B per K-step (2x 1KB chunks each).
  auto stage = [&](int buf, int ks) {
    int k0 = ks * BK;
    int t0 = wid * 2;  // chunk index, chunk = 16 rows
    const ushort* gA = cbf + (size_t)(r0 + t0*16 + lrow) * DIM + k0 + lk;
    async16(gA,            &Al[buf][t0*16][0]);
    async16(gA + 16*DIM,   &Al[buf][t0*16 + 16][0]);
    const ushort* gB = pbf + (size_t)(c0 + t0*16 + lrow) * DIM + k0 + lk;
    async16(gB,            &Bl[buf][t0*16][0]);
    async16(gB + 16*DIM,   &Bl[buf][t0*16 + 16][0]);
  };

  f32x4 acc[4][4];   // [n][m]
  #pragma unroll
  for (int n = 0; n < 4; ++n)
    #pragma unroll
    for (int m = 0; m < 4; ++m)
      acc[n][m] = (f32x4){0.f, 0.f, 0.f, 0.f};

  const int wr = wid >> 1, wc = wid & 1;   // 2x2 wave grid, 64x64 per wave
  const int rb = wr * 64, cbase = wc * 64;
  const int frow = lane & 15;
  const int fk = (((lane >> 4) ^ ((frow >> 1) & 3)) * 8);  // swizzled read

  stage(0, 0);
  #pragma unroll
  for (int ks = 0; ks < DIM / BK; ++ks) {
    __syncthreads();                       // staged tile ks is ready
    if (ks < DIM / BK - 1) stage((ks + 1) & 1, ks + 1);
    int buf = ks & 1;
    short8 af[4], bfr[4];
    #pragma unroll
    for (int m = 0; m < 4; ++m)
      af[m] = *(const short8*)&Al[buf][rb + m*16 + frow][fk];
    #pragma unroll
    for (int n = 0; n < 4; ++n)
      bfr[n] = *(const short8*)&Bl[buf][cbase + n*16 + frow][fk];
    // SWAPPED: A-operand = prev fragment, B-operand = curr fragment.
    // => D rows (lane>>4)*4+reg = prev col j, D cols lane&15 = curr row i.
    #pragma unroll
    for (int n = 0; n < 4; ++n)
      #pragma unroll
      for (int m = 0; m < 4; ++m)
        acc[n][m] = __builtin_amdgcn_mfma_f32_16x16x32_bf16(bfr[n], af[m], acc[n][m], 0, 0, 0);
  }

  // Epilogue: lane owns row i = rb + m*16 + (lane&15),
  //           cols j = cbase + n*16 + (lane>>4)*4 + r  (4 consecutive).
  float lp = 0.f;
  const int fi = lane & 15;
  const int g4 = (lane >> 4) << 2;
  #pragma unroll
  for (int m = 0; m < 4; ++m) {
    int il = rb + m*16 + fi;
    float4 rv = rowv[il];
    int rid = ridl[il];
    float* orow = out + (size_t)(r0 + il) * M_PREV + c0;
    #pragma unroll
    for (int n = 0; n < 4; ++n) {
      int jl0 = cbase + n*16 + g4;
      f32x4 res;
      #pragma unroll
      for (int r = 0; r < 4; ++r) {
        int jl = jl0 + r;
        float4 cv = colv[jl];
        float dot = acc[n][m][r];
        float w = rv.x * cv.x;                   // invc * 0.7*invp
        float dx = rv.z - cv.z;
        float dy = rv.w - cv.w;
        float ccd = __builtin_amdgcn_sqrtf(dx*dx + dy*dy);
        res[r] = fmaf(0.3f, ccd, fmaf(-w, dot, 0.7f));
        float d2 = fmaxf(rv.y + cv.y - 2.0f * dot, 0.0f);
        float dist = __builtin_amdgcn_sqrtf(d2);
        float tt = fmaxf(1.0f - dist, 0.0f);
        lp += (rid == cidl[jl]) ? d2 : tt * tt;
      }
      *(f32x4*)(orow + jl0) = res;
    }
  }

  #pragma unroll
  for (int m = 32; m; m >>= 1) lp += __shfl_xor(lp, m);
  if (lane == 0) wsum[wid] = lp;
  __syncthreads();
  if (tid == 0) partials[bid] = (wsum[0] + wsum[1]) + (wsum[2] + wsum[3]);
}

// Deterministic fixed-order reduction of block partials.
__global__ __launch_bounds__(256) void finalize_loss(
    const float* __restrict__ partials, float* __restrict__ loss_out)
{
  __shared__ float sh[4];
  float s = 0.f;
  for (int i = threadIdx.x; i < NBLK; i += 256) s += partials[i];
  #pragma unroll
  for (int m = 32; m; m >>= 1) s += __shfl_xor(s, m);
  if ((threadIdx.x & 63) == 0) sh[threadIdx.x >> 6] = s;
  __syncthreads();
  if (threadIdx.x == 0)
    loss_out[0] = ((sh[0] + sh[1]) + (sh[2] + sh[3])) * (1.0f / 41943040.0f);
}

extern "C" void kernel_launch(void* const* d_in, const int* in_sizes, int n_in,
                              void* d_out, int out_size, void* d_ws, size_t ws_size,
                              hipStream_t stream) {
  const float* ce  = (const float*)d_in[0];
  const float* cbx = (const float*)d_in[1];
  const float* pe  = (const float*)d_in[2];
  const float* pbx = (const float*)d_in[3];
  const int*   cid = (const int*)d_in[4];
  const int*   pid = (const int*)d_in[5];
  float* out = (float*)d_out;

  char* ws = (char*)d_ws;
  ushort* cbf = (ushort*)ws;                        // 4096*256*2  = 2 MB
  ushort* pbf = (ushort*)(ws + (2u << 20));         // 10240*256*2 = 5 MB
  float4* cpar = (float4*)(ws + 7340032);           // 64 KB
  float4* ppar = (float4*)(ws + 7340032 + 65536);   // 160 KB
  float* partials = (float*)(ws + 7340032 + 65536 + 163840);  // 10 KB

  prep_kernel<<<(N_CURR + M_PREV) / 4, 256, 0, stream>>>(
      ce, cbx, pe, pbx, cbf, pbf, cpar, ppar);
  main_kernel<<<NBLK, 256, 0, stream>>>(
      cbf, pbf, cpar, ppar, cid, pid, out, partials);
  finalize_loss<<<1, 256, 0, stream>>>(partials, out + (size_t)N_CURR * M_PREV);
}

// Round 6
// 72.361 us; speedup vs baseline: 1.9240x; 1.5565x over previous
//
#include <hip/hip_runtime.h>
#include <hip/hip_bf16.h>

#define N_CURR 4096
#define M_PREV 10240
#define DIM 256
#define BM 128
#define BN 128
#define BK 32
#define NBX (M_PREV / BN)   // 80
#define NBY (N_CURR / BM)   // 32
#define NBLK (NBX * NBY)    // 2560

typedef short short8 __attribute__((ext_vector_type(8)));
typedef float f32x4 __attribute__((ext_vector_type(4)));

__device__ __forceinline__ unsigned short f2bf(float f) {
  union { float f; unsigned int u; } x; x.f = f;
  unsigned int u = x.u;
  return (unsigned short)((u + 0x7fffu + ((u >> 16) & 1u)) >> 16);  // RNE
}

__device__ __forceinline__ void async16(const void* g, void* l) {
  __builtin_amdgcn_global_load_lds(
      (const __attribute__((address_space(1))) unsigned int*)g,
      (__attribute__((address_space(3))) unsigned int*)l, 16, 0, 0);
}

// One wave per row: squared norm, inv-norm, bf16 cast, centers.
// Packs {invn, |x|^2, cx, cy} into one float4 per row.
__global__ __launch_bounds__(256) void prep_kernel(
    const float* __restrict__ ce, const float* __restrict__ cbx,
    const float* __restrict__ pe, const float* __restrict__ pbx,
    ushort* __restrict__ cbf, ushort* __restrict__ pbf,
    float4* __restrict__ cpar, float4* __restrict__ ppar)
{
  int gw = (blockIdx.x * 256 + threadIdx.x) >> 6;   // global wave = row
  int lane = threadIdx.x & 63;
  bool isCurr = gw < N_CURR;
  int row = isCurr ? gw : gw - N_CURR;
  const float* src = (isCurr ? ce : pe) + (size_t)row * DIM;
  ushort* dst = (isCurr ? cbf : pbf) + (size_t)row * DIM;

  float4 v = ((const float4*)src)[lane];            // 64 lanes x 16B = full row
  ushort4 b;
  b.x = f2bf(v.x); b.y = f2bf(v.y); b.z = f2bf(v.z); b.w = f2bf(v.w);
  ((ushort4*)dst)[lane] = b;

  float s = v.x*v.x + v.y*v.y + v.z*v.z + v.w*v.w;
  #pragma unroll
  for (int m = 32; m; m >>= 1) s += __shfl_xor(s, m);

  if (lane == 0) {
    float nrm = fmaxf(__builtin_amdgcn_sqrtf(s), 1e-12f);
    float4 bb = ((const float4*)(isCurr ? cbx : pbx))[row];
    float4 par;
    par.x = 1.0f / nrm;           // inv norm
    par.y = s;                    // squared norm
    par.z = bb.x + 0.5f * bb.z;   // center x
    par.w = bb.y + 0.5f * bb.w;   // center y
    (isCurr ? cpar : ppar)[row] = par;
  }
}

// 128x128 block tile, 512 threads = 8 waves, wave tile 64x32.
// Live set ~90 regs/lane -> 4 waves/SIMD (2 blocks/CU) without spills.
// MFMA operands swapped (A=prev, B=curr): lane's 4 acc regs are 4
// consecutive prev-columns -> float4 stores.
__global__ __launch_bounds__(512) void main_kernel(
    const ushort* __restrict__ cbf, const ushort* __restrict__ pbf,
    const float4* __restrict__ cpar, const float4* __restrict__ ppar,
    const int* __restrict__ cid, const int* __restrict__ pid,
    float* __restrict__ out, float* __restrict__ partials)
{
  __shared__ __align__(16) ushort Al[2][BM][BK];   // 16 KB
  __shared__ __align__(16) ushort Bl[2][BN][BK];   // 16 KB
  __shared__ float4 rowv[BM];                      // {invnc, c2, cx, cy}
  __shared__ float4 colv[BN];                      // {0.7*invnp, p2, px, py}
  __shared__ int ridl[BM];
  __shared__ int cidl[BN];
  __shared__ float wsum[8];

  const int bid = blockIdx.x;
  const int bx = bid % NBX;
  const int by = bid / NBX;
  const int r0 = by * BM;
  const int c0 = bx * BN;
  const int tid = threadIdx.x;
  const int lane = tid & 63;
  const int wid = tid >> 6;

  const int lrow = lane >> 2;                       // 0..15 row within chunk
  // Source-side XOR swizzle (chunk ^= (row>>1)&3) so LDS reads are 2-way max.
  const int lk = (((lane & 3) ^ ((lrow >> 1) & 3)) * 8);

  // Per K-step each wave stages 16 rows of A and 16 rows of B (1 KB each).
  auto stage = [&](int buf, int ks) {
    int k0 = ks * BK;
    const ushort* gA = cbf + (size_t)(r0 + wid*16 + lrow) * DIM + k0 + lk;
    async16(gA, &Al[buf][wid*16][0]);
    const ushort* gB = pbf + (size_t)(c0 + wid*16 + lrow) * DIM + k0 + lk;
    async16(gB, &Bl[buf][wid*16][0]);
  };

  stage(0, 0);   // first tile in flight before anything else

  // Stage per-row / per-col params into LDS (covered by first loop barrier).
  if (tid < BM) {
    rowv[tid] = cpar[r0 + tid];
    ridl[tid] = cid[r0 + tid];
  } else if (tid < 2 * BM) {
    int t = tid - BM;
    float4 pv = ppar[c0 + t];
    pv.x *= 0.7f;                                  // pre-scale by ALPHA
    colv[t] = pv;
    cidl[t] = pid[c0 + t];
  }

  f32x4 acc[2][4];   // [n][m]
  #pragma unroll
  for (int n = 0; n < 2; ++n)
    #pragma unroll
    for (int m = 0; m < 4; ++m)
      acc[n][m] = (f32x4){0.f, 0.f, 0.f, 0.f};

  const int wr = wid >> 2, wc = wid & 3;   // 2x4 wave grid, 64x32 per wave
  const int rb = wr * 64, cbase = wc * 32;
  const int frow = lane & 15;
  const int fk = (((lane >> 4) ^ ((frow >> 1) & 3)) * 8);  // swizzled read

  #pragma unroll
  for (int ks = 0; ks < DIM / BK; ++ks) {
    __syncthreads();                       // staged tile ks is ready
    if (ks < DIM / BK - 1) stage((ks + 1) & 1, ks + 1);
    int buf = ks & 1;
    short8 af[4], bfr[2];
    #pragma unroll
    for (int m = 0; m < 4; ++m)
      af[m] = *(const short8*)&Al[buf][rb + m*16 + frow][fk];
    #pragma unroll
    for (int n = 0; n < 2; ++n)
      bfr[n] = *(const short8*)&Bl[buf][cbase + n*16 + frow][fk];
    // SWAPPED: A-operand = prev fragment, B-operand = curr fragment.
    // => D rows (lane>>4)*4+reg = prev col j, D cols lane&15 = curr row i.
    #pragma unroll
    for (int n = 0; n < 2; ++n)
      #pragma unroll
      for (int m = 0; m < 4; ++m)
        acc[n][m] = __builtin_amdgcn_mfma_f32_16x16x32_bf16(bfr[n], af[m], acc[n][m], 0, 0, 0);
  }

  // Epilogue: lane owns row i = rb + m*16 + (lane&15),
  //           cols j = cbase + n*16 + (lane>>4)*4 + r  (4 consecutive).
  float lp = 0.f;
  const int fi = lane & 15;
  const int g4 = (lane >> 4) << 2;
  #pragma unroll
  for (int m = 0; m < 4; ++m) {
    int il = rb + m*16 + fi;
    float4 rv = rowv[il];
    int rid = ridl[il];
    float* orow = out + (size_t)(r0 + il) * M_PREV + c0;
    #pragma unroll
    for (int n = 0; n < 2; ++n) {
      int jl0 = cbase + n*16 + g4;
      f32x4 res;
      #pragma unroll
      for (int r = 0; r < 4; ++r) {
        int jl = jl0 + r;
        float4 cv = colv[jl];
        float dot = acc[n][m][r];
        float w = rv.x * cv.x;                   // invc * 0.7*invp
        float dx = rv.z - cv.z;
        float dy = rv.w - cv.w;
        float ccd = __builtin_amdgcn_sqrtf(dx*dx + dy*dy);
        res[r] = fmaf(0.3f, ccd, fmaf(-w, dot, 0.7f));
        float d2 = fmaxf(rv.y + cv.y - 2.0f * dot, 0.0f);
        float dist = __builtin_amdgcn_sqrtf(d2);
        float tt = fmaxf(1.0f - dist, 0.0f);
        lp += (rid == cidl[jl]) ? d2 : tt * tt;
      }
      *(f32x4*)(orow + jl0) = res;
    }
  }

  #pragma unroll
  for (int m = 32; m; m >>= 1) lp += __shfl_xor(lp, m);
  if (lane == 0) wsum[wid] = lp;
  __syncthreads();
  if (tid == 0) {
    float s = 0.f;
    #pragma unroll
    for (int w = 0; w < 8; ++w) s += wsum[w];
    partials[bid] = s;
  }
}

// Deterministic fixed-order reduction of block partials.
__global__ __launch_bounds__(256) void finalize_loss(
    const float* __restrict__ partials, float* __restrict__ loss_out)
{
  __shared__ float sh[4];
  float s = 0.f;
  for (int i = threadIdx.x; i < NBLK; i += 256) s += partials[i];
  #pragma unroll
  for (int m = 32; m; m >>= 1) s += __shfl_xor(s, m);
  if ((threadIdx.x & 63) == 0) sh[threadIdx.x >> 6] = s;
  __syncthreads();
  if (threadIdx.x == 0)
    loss_out[0] = ((sh[0] + sh[1]) + (sh[2] + sh[3])) * (1.0f / 41943040.0f);
}

extern "C" void kernel_launch(void* const* d_in, const int* in_sizes, int n_in,
                              void* d_out, int out_size, void* d_ws, size_t ws_size,
                              hipStream_t stream) {
  const float* ce  = (const float*)d_in[0];
  const float* cbx = (const float*)d_in[1];
  const float* pe  = (const float*)d_in[2];
  const float* pbx = (const float*)d_in[3];
  const int*   cid = (const int*)d_in[4];
  const int*   pid = (const int*)d_in[5];
  float* out = (float*)d_out;

  char* ws = (char*)d_ws;
  ushort* cbf = (ushort*)ws;                        // 4096*256*2  = 2 MB
  ushort* pbf = (ushort*)(ws + (2u << 20));         // 10240*256*2 = 5 MB
  float4* cpar = (float4*)(ws + 7340032);           // 64 KB
  float4* ppar = (float4*)(ws + 7340032 + 65536);   // 160 KB
  float* partials = (float*)(ws + 7340032 + 65536 + 163840);  // 10 KB

  prep_kernel<<<(N_CURR + M_PREV) / 4, 256, 0, stream>>>(
      ce, cbx, pe, pbx, cbf, pbf, cpar, ppar);
  main_kernel<<<NBLK, 512, 0, stream>>>(
      cbf, pbf, cpar, ppar, cid, pid, out, partials);
  finalize_loss<<<1, 256, 0, stream>>>(partials, out + (size_t)N_CURR * M_PREV);
}

// Round 7
// 68.548 us; speedup vs baseline: 2.0310x; 1.0556x over previous
//
#include <hip/hip_runtime.h>
#include <hip/hip_bf16.h>

#define N_CURR 4096
#define M_PREV 10240
#define DIM 256
#define BM 128
#define BN 128
#define BK2 64
#define NBX (M_PREV / BN)   // 80
#define NBY (N_CURR / BM)   // 32
#define NBLK (NBX * NBY)    // 2560

typedef short short8 __attribute__((ext_vector_type(8)));
typedef float f32x4 __attribute__((ext_vector_type(4)));

__device__ __forceinline__ unsigned short f2bf(float f) {
  union { float f; unsigned int u; } x; x.f = f;
  unsigned int u = x.u;
  return (unsigned short)((u + 0x7fffu + ((u >> 16) & 1u)) >> 16);  // RNE
}

__device__ __forceinline__ void async16(const void* g, void* l) {
  __builtin_amdgcn_global_load_lds(
      (const __attribute__((address_space(1))) unsigned int*)g,
      (__attribute__((address_space(3))) unsigned int*)l, 16, 0, 0);
}

// One wave per row: squared norm, inv-norm, bf16 cast, centers.
// Packs {invn, |x|^2, cx, cy} into one float4 per row.
__global__ __launch_bounds__(256) void prep_kernel(
    const float* __restrict__ ce, const float* __restrict__ cbx,
    const float* __restrict__ pe, const float* __restrict__ pbx,
    ushort* __restrict__ cbf, ushort* __restrict__ pbf,
    float4* __restrict__ cpar, float4* __restrict__ ppar)
{
  int gw = (blockIdx.x * 256 + threadIdx.x) >> 6;   // global wave = row
  int lane = threadIdx.x & 63;
  bool isCurr = gw < N_CURR;
  int row = isCurr ? gw : gw - N_CURR;
  const float* src = (isCurr ? ce : pe) + (size_t)row * DIM;
  ushort* dst = (isCurr ? cbf : pbf) + (size_t)row * DIM;

  float4 v = ((const float4*)src)[lane];            // 64 lanes x 16B = full row
  ushort4 b;
  b.x = f2bf(v.x); b.y = f2bf(v.y); b.z = f2bf(v.z); b.w = f2bf(v.w);
  ((ushort4*)dst)[lane] = b;

  float s = v.x*v.x + v.y*v.y + v.z*v.z + v.w*v.w;
  #pragma unroll
  for (int m = 32; m; m >>= 1) s += __shfl_xor(s, m);

  if (lane == 0) {
    float nrm = fmaxf(__builtin_amdgcn_sqrtf(s), 1e-12f);
    float4 bb = ((const float4*)(isCurr ? cbx : pbx))[row];
    float4 par;
    par.x = 1.0f / nrm;           // inv norm
    par.y = s;                    // squared norm
    par.z = bb.x + 0.5f * bb.z;   // center x
    par.w = bb.y + 0.5f * bb.w;   // center y
    (isCurr ? cpar : ppar)[row] = par;
  }
}

// 128x128 block tile, 512 threads = 8 waves, wave tile 64x32, BK=64
// (4 barriers per block instead of 8). LDS rows are 128B; reads use the
// chunk^=(row&7) XOR swizzle, applied on the SOURCE side for staging
// (global_load_lds writes linearly) and on the chunk index for ds_read.
__global__ __launch_bounds__(512, 4) void main_kernel(
    const ushort* __restrict__ cbf, const ushort* __restrict__ pbf,
    const float4* __restrict__ cpar, const float4* __restrict__ ppar,
    const int* __restrict__ cid, const int* __restrict__ pid,
    float* __restrict__ out, float* __restrict__ partials)
{
  __shared__ __align__(16) ushort Al[2][BM][BK2];  // 32 KB
  __shared__ __align__(16) ushort Bl[2][BN][BK2];  // 32 KB
  __shared__ float4 rowv[BM];                      // {invnc, c2, cx, cy}
  __shared__ float4 colv[BN];                      // {0.7*invnp, p2, px, py}
  __shared__ int ridl[BM];
  __shared__ int cidl[BN];
  __shared__ float wsum[8];

  const int bid = blockIdx.x;
  const int bx = bid % NBX;
  const int by = bid / NBX;
  const int r0 = by * BM;
  const int c0 = bx * BN;
  const int tid = threadIdx.x;
  const int lane = tid & 63;
  const int wid = tid >> 6;

  // Stage-side swizzle: lane l writes LDS row (base + l>>3), chunk l&7.
  // We want LDS[r][c] = global element ((c ^ (r&7))*8), so lane l's global
  // col chunk is (l&7) ^ (l>>3).
  const int sr = lane >> 3;                  // 0..7 row within 8-row group
  const int sc = ((lane & 7) ^ sr) * 8;      // swizzled source col (elements)

  // Per K-step each wave stages 16 rows of A and 16 rows of B (2 KB each,
  // 4 async16). Row groups: wave wid owns rows wid*16 .. wid*16+15.
  auto stage = [&](int buf, int ks) {
    const int k0 = ks * BK2;
    const int rA = wid * 16 + sr;
    const ushort* gA = cbf + (size_t)(r0 + rA) * DIM + k0 + sc;
    async16(gA,           &Al[buf][wid*16][0]);
    async16(gA + 8*DIM,   &Al[buf][wid*16 + 8][0]);
    const ushort* gB = pbf + (size_t)(c0 + rA) * DIM + k0 + sc;
    async16(gB,           &Bl[buf][wid*16][0]);
    async16(gB + 8*DIM,   &Bl[buf][wid*16 + 8][0]);
  };

  stage(0, 0);   // first tile in flight before anything else

  // Stage per-row / per-col params into LDS (covered by first loop barrier).
  if (tid < BM) {
    rowv[tid] = cpar[r0 + tid];
    ridl[tid] = cid[r0 + tid];
  } else if (tid < 2 * BM) {
    int t = tid - BM;
    float4 pv = ppar[c0 + t];
    pv.x *= 0.7f;                                  // pre-scale by ALPHA
    colv[t] = pv;
    cidl[t] = pid[c0 + t];
  }

  f32x4 acc[2][4];   // [n][m]
  #pragma unroll
  for (int n = 0; n < 2; ++n)
    #pragma unroll
    for (int m = 0; m < 4; ++m)
      acc[n][m] = (f32x4){0.f, 0.f, 0.f, 0.f};

  const int wr = wid >> 2, wc = wid & 3;   // 2x4 wave grid, 64x32 per wave
  const int rb = wr * 64, cbase = wc * 32;
  const int frow = lane & 15;
  const int f7 = frow & 7;                 // row&7 for every fragment row
  const int cko = lane >> 4;               // base chunk 0..3

  #pragma unroll
  for (int ks = 0; ks < DIM / BK2; ++ks) {
    __syncthreads();                       // staged tile ks is ready
    if (ks < DIM / BK2 - 1) stage((ks + 1) & 1, ks + 1);
    const int buf = ks & 1;
    #pragma unroll
    for (int half = 0; half < 2; ++half) {
      const int cc = ((half * 4 + cko) ^ f7) * 16;   // swizzled byte chunk
      short8 af[4], bfr[2];
      #pragma unroll
      for (int m = 0; m < 4; ++m)
        af[m] = *(const short8*)((const char*)&Al[buf][rb + m*16 + frow][0] + cc);
      #pragma unroll
      for (int n = 0; n < 2; ++n)
        bfr[n] = *(const short8*)((const char*)&Bl[buf][cbase + n*16 + frow][0] + cc);
      // SWAPPED: A-operand = prev fragment, B-operand = curr fragment.
      // => D rows (lane>>4)*4+reg = prev col j, D cols lane&15 = curr row i.
      #pragma unroll
      for (int n = 0; n < 2; ++n)
        #pragma unroll
        for (int m = 0; m < 4; ++m)
          acc[n][m] = __builtin_amdgcn_mfma_f32_16x16x32_bf16(bfr[n], af[m], acc[n][m], 0, 0, 0);
    }
  }

  // Epilogue: lane owns row i = rb + m*16 + (lane&15),
  //           cols j = cbase + n*16 + (lane>>4)*4 + r  (4 consecutive).
  float lp = 0.f;
  const int g4 = (lane >> 4) << 2;
  #pragma unroll
  for (int m = 0; m < 4; ++m) {
    int il = rb + m*16 + frow;
    float4 rv = rowv[il];
    int rid = ridl[il];
    float* orow = out + (size_t)(r0 + il) * M_PREV + c0;
    #pragma unroll
    for (int n = 0; n < 2; ++n) {
      int jl0 = cbase + n*16 + g4;
      f32x4 res;
      #pragma unroll
      for (int r = 0; r < 4; ++r) {
        int jl = jl0 + r;
        float4 cv = colv[jl];
        float dot = acc[n][m][r];
        float w = rv.x * cv.x;                   // invc * 0.7*invp
        float dx = rv.z - cv.z;
        float dy = rv.w - cv.w;
        float ccd = __builtin_amdgcn_sqrtf(dx*dx + dy*dy);
        res[r] = fmaf(0.3f, ccd, fmaf(-w, dot, 0.7f));
        float d2 = fmaxf(rv.y + cv.y - 2.0f * dot, 0.0f);
        float dist = __builtin_amdgcn_sqrtf(d2);
        float tt = fmaxf(1.0f - dist, 0.0f);
        lp += (rid == cidl[jl]) ? d2 : tt * tt;
      }
      *(f32x4*)(orow + jl0) = res;
    }
  }

  #pragma unroll
  for (int m = 32; m; m >>= 1) lp += __shfl_xor(lp, m);
  if (lane == 0) wsum[wid] = lp;
  __syncthreads();
  if (tid == 0) {
    float s = 0.f;
    #pragma unroll
    for (int w = 0; w < 8; ++w) s += wsum[w];
    partials[bid] = s;
  }
}

// Deterministic fixed-order reduction of block partials.
__global__ __launch_bounds__(256) void finalize_loss(
    const float* __restrict__ partials, float* __restrict__ loss_out)
{
  __shared__ float sh[4];
  float s = 0.f;
  for (int i = threadIdx.x; i < NBLK; i += 256) s += partials[i];
  #pragma unroll
  for (int m = 32; m; m >>= 1) s += __shfl_xor(s, m);
  if ((threadIdx.x & 63) == 0) sh[threadIdx.x >> 6] = s;
  __syncthreads();
  if (threadIdx.x == 0)
    loss_out[0] = ((sh[0] + sh[1]) + (sh[2] + sh[3])) * (1.0f / 41943040.0f);
}

extern "C" void kernel_launch(void* const* d_in, const int* in_sizes, int n_in,
                              void* d_out, int out_size, void* d_ws, size_t ws_size,
                              hipStream_t stream) {
  const float* ce  = (const float*)d_in[0];
  const float* cbx = (const float*)d_in[1];
  const float* pe  = (const float*)d_in[2];
  const float* pbx = (const float*)d_in[3];
  const int*   cid = (const int*)d_in[4];
  const int*   pid = (const int*)d_in[5];
  float* out = (float*)d_out;

  char* ws = (char*)d_ws;
  ushort* cbf = (ushort*)ws;                        // 4096*256*2  = 2 MB
  ushort* pbf = (ushort*)(ws + (2u << 20));         // 10240*256*2 = 5 MB
  float4* cpar = (float4*)(ws + 7340032);           // 64 KB
  float4* ppar = (float4*)(ws + 7340032 + 65536);   // 160 KB
  float* partials = (float*)(ws + 7340032 + 65536 + 163840);  // 10 KB

  prep_kernel<<<(N_CURR + M_PREV) / 4, 256, 0, stream>>>(
      ce, cbx, pe, pbx, cbf, pbf, cpar, ppar);
  main_kernel<<<NBLK, 512, 0, stream>>>(
      cbf, pbf, cpar, ppar, cid, pid, out, partials);
  finalize_loss<<<1, 256, 0, stream>>>(partials, out + (size_t)N_CURR * M_PREV);
}